// Round 2
// baseline (12893.532 us; speedup 1.0000x reference)
//
#include <hip/hip_runtime.h>
#include <hip/hip_fp16.h>
#include <stdint.h>
#include <stddef.h>

// DRNN (dilated 3-layer LSTM), B=128, T=1024, F=128, H=256, dil=[1,2,4].
// Strategy:
//  - Hoist all input-to-hidden GEMMs out of the recurrence: G = inp @ W_ih^T + (b_ih+b_hh),
//    done with f16 MFMA (16x16x32) in 67MB time-chunks.
//  - Recurrence: one batch element per PAIR of workgroups (512 gate cols each).
//    W_hh half-slice lives in VGPRs (1 col/thread, 128 x half2). h broadcast via
//    v_readlane + v_dot2_f32_f16. Pair exchanges h halves per step through MALL
//    (agent-scope atomics; per-XCD L2 not coherent). Grid 256 <= capacity -> co-resident.
//  - f16 storage / fp32 accumulation; c-state fp32. Threshold is 2% of |ref|max.

typedef _Float16 f16;
typedef _Float16 v2h __attribute__((ext_vector_type(2)));
typedef _Float16 v8h __attribute__((ext_vector_type(8)));
typedef __fp16 h2_raw __attribute__((ext_vector_type(2)));
typedef __fp16 h8_raw __attribute__((ext_vector_type(8)));
typedef float v4f __attribute__((ext_vector_type(4)));

#define DEVINL static __device__ __forceinline__

DEVINL float sigm(float x) { return 1.0f / (1.0f + __expf(-x)); }
DEVINL float tanh_(float x) {
  x = fminf(fmaxf(x, -15.0f), 15.0f);
  float e = __expf(-2.0f * x);
  return (1.0f - e) / (1.0f + e);
}
DEVINL v2h pack2(float a, float b) {
  return __builtin_bit_cast(v2h, __builtin_amdgcn_cvt_pkrtz(a, b));
}
DEVINL v2h bcast_pair(v2h v, int l) {
  int i = __builtin_bit_cast(int, v);
  i = __builtin_amdgcn_readlane(i, l);
  return __builtin_bit_cast(v2h, i);
}
DEVINL float fdot2(v2h a, v2h b, float c) {
  return __builtin_amdgcn_fdot2(__builtin_bit_cast(h2_raw, a),
                                __builtin_bit_cast(h2_raw, b), c, false);
}
DEVINL v4f mfma_16x16x32(v8h a, v8h b, v4f c) {
  return __builtin_amdgcn_mfma_f32_16x16x32_f16(__builtin_bit_cast(h8_raw, a),
                                                __builtin_bit_cast(h8_raw, b), c,
                                                0, 0, 0);
}

// ---------------- prep: fp32 -> f16 conversions ----------------

__global__ void k_cvt_x(const float2* __restrict__ src, v2h* __restrict__ dst, int n2) {
  int i = blockIdx.x * blockDim.x + threadIdx.x;
  int st = gridDim.x * blockDim.x;
  for (; i < n2; i += st) {
    float2 v = src[i];
    dst[i] = pack2(v.x, v.y);
  }
}

__global__ void k_prep_w(const float* __restrict__ wih0, const float* __restrict__ whh0,
                         const float* __restrict__ wih1, const float* __restrict__ whh1,
                         const float* __restrict__ wih2, const float* __restrict__ whh2,
                         const float* __restrict__ bi0, const float* __restrict__ bh0,
                         const float* __restrict__ bi1, const float* __restrict__ bh1,
                         const float* __restrict__ bi2, const float* __restrict__ bh2,
                         f16* wih0f, f16* whh0f, f16* wih1f, f16* whh1f,
                         f16* wih2f, f16* whh2f,
                         float* bias0, float* bias1, float* bias2) {
  int i = blockIdx.x * blockDim.x + threadIdx.x;  // grid covers 262144
  if (i < 131072) wih0f[i] = (f16)wih0[i];
  whh0f[i] = (f16)whh0[i];
  wih1f[i] = (f16)wih1[i];
  whh1f[i] = (f16)whh1[i];
  wih2f[i] = (f16)wih2[i];
  whh2f[i] = (f16)whh2[i];
  if (i < 1024) {
    bias0[i] = bi0[i] + bh0[i];
    bias1[i] = bi1[i] + bh1[i];
    bias2[i] = bi2[i] + bh2[i];
  }
}

// ---------------- input GEMM: G[b][tloc][1024] = A[b][t0+tloc][:K] @ W^T + bias ----------------
// grid = 128*4 blocks (b = blk>>2, tb = blk&3 -> 64 rows each), 256 threads (4 waves).
// MFMA f32_16x16x32_f16; A-frag: m=lane&15, k=(lane>>4)*8+j; B-frag: n=lane&15 (W row), same k.
// C/D: col=lane&15, row=(lane>>4)*4+reg  [verified layouts, guide §3].

template <int K>
__launch_bounds__(256)
__global__ void k_gemm(const f16* __restrict__ A, int Tb, int t0,
                       const f16* __restrict__ W, const float* __restrict__ bias,
                       f16* __restrict__ G) {
  constexpr int LDK = K + 8;  // pad to break LDS bank conflicts on frag reads
  __shared__ f16 As[64 * LDK];
  int b = blockIdx.x >> 2, tb = blockIdx.x & 3;
  const f16* Ablk = A + ((size_t)b * Tb + t0 + tb * 64) * K;
  int tid = threadIdx.x;

  // stage A tile (64 x K, contiguous rows) into LDS
  constexpr int NV = 64 * K / 8;  // uint4 count
  const uint4* src = (const uint4*)Ablk;
  for (int i = tid; i < NV; i += 256) {
    int e = i * 8;
    int r = e / K, c0 = e % K;
    *(uint4*)&As[r * LDK + c0] = src[i];
  }
  __syncthreads();

  int wave = tid >> 6, lane = tid & 63;
  int lm = lane & 15, lk = (lane >> 4) * 8;

  v8h af[K / 32];
#pragma unroll
  for (int kc = 0; kc < K / 32; ++kc)
    af[kc] = *(const v8h*)&As[(wave * 16 + lm) * LDK + kc * 32 + lk];

  size_t grow0 = (size_t)b * 256 + tb * 64 + wave * 16;
  for (int nt = 0; nt < 64; ++nt) {
    v4f acc = {0.0f, 0.0f, 0.0f, 0.0f};
    const f16* Wrow = W + (size_t)(nt * 16 + lm) * K + lk;
#pragma unroll
    for (int kc = 0; kc < K / 32; ++kc) {
      v8h bf = *(const v8h*)(Wrow + kc * 32);
      acc = mfma_16x16x32(af[kc], bf, acc);
    }
    float bv = bias[nt * 16 + lm];
#pragma unroll
    for (int r = 0; r < 4; ++r) {
      int m = (lane >> 4) * 4 + r;
      G[(grow0 + m) * 1024 + nt * 16 + lm] = (f16)(acc[r] + bv);
    }
  }
}

// ---------------- recurrence ----------------
// grid 256 blocks x 512 threads. pair(b)=blk>>1, half=blk&1 owns gate cols
// {g*256 + half*128 + j : g<4, j<128} == all 4 gates for h dims [half*128, half*128+128).
// Thread t: g=t>>7, j=t&127, col = g*256+half*128+j. W_hh row in regs as 128 x half2,
// first 64 pairs = own-half k (computable before partner h arrives).
// LAYER: 0 -> store h0 at even t into Hout[b][t/2]; 1 -> h1 at even t into Hout[b][t/2];
// 2 -> y[b][4t..4t+3] = h2.

template <int LAYER>
__launch_bounds__(512, 2)
__global__ void k_rec(const f16* __restrict__ G,   // chunk [128][256][1024]
                      const f16* __restrict__ Whh, // [1024][256] f16
                      int t0, int steps,
                      f16* __restrict__ Hout, float* __restrict__ y,
                      float* __restrict__ hstate, float* __restrict__ cstate,
                      float* hx, int* flags) {
  int blk = blockIdx.x;
  int b = blk >> 1, half = blk & 1;
  int tid = threadIdx.x;
  int lane = tid & 63;
  int g = tid >> 7, j = tid & 127;
  int col = g * 256 + half * 128 + j;

  __shared__ float gbuf[512];
  __shared__ float hbuf[256];

  // W_hh row for this col -> registers. w0: own-half k, w1: partner-half k.
  v2h w0[64], w1[64];
  {
    const v8h* wown = (const v8h*)(Whh + (size_t)col * 256 + half * 128);
    const v8h* woth = (const v8h*)(Whh + (size_t)col * 256 + (1 - half) * 128);
#pragma unroll
    for (int i = 0; i < 16; ++i) {
      v8h qa = wown[i], qb = woth[i];
#pragma unroll
      for (int p = 0; p < 4; ++p) {
        v2h ta, tb;
        ta[0] = qa[2 * p]; ta[1] = qa[2 * p + 1];
        tb[0] = qb[2 * p]; tb[1] = qb[2 * p + 1];
        w0[i * 4 + p] = ta;
        w1[i * 4 + p] = tb;
      }
    }
  }

  float c_st = 0.0f;
  v2h hp_own = pack2(0.0f, 0.0f), hp_oth = pack2(0.0f, 0.0f);

  if (t0 > 0) {  // restore chunk state (full h + own-half c)
    if (tid < 256) hbuf[tid] = hstate[b * 256 + tid];
    __syncthreads();
    if (tid < 128) c_st = cstate[b * 256 + half * 128 + tid];
    float2 a = *(const float2*)&hbuf[half * 128 + 2 * lane];
    hp_own = pack2(a.x, a.y);
    float2 o = *(const float2*)&hbuf[(1 - half) * 128 + 2 * lane];
    hp_oth = pack2(o.x, o.y);
  }

  const f16* Gp = G + (size_t)b * 256 * 1024 + col;
  int* flag_me = &flags[b * 2 + half];
  int* flag_pt = &flags[b * 2 + (1 - half)];
  float* hx_me = &hx[b * 256 + half * 128];
  float* hx_pt = &hx[b * 256 + (1 - half) * 128];

  for (int s = 0; s < steps; ++s) {
    int t = t0 + s;
    float acc = (float)Gp[(size_t)s << 10];

    // own-half contribution first (hides partner exchange latency)
#pragma unroll
    for (int kk = 0; kk < 64; ++kk)
      acc = fdot2(w0[kk], bcast_pair(hp_own, kk), acc);

    if (t > 0) {  // import partner half of h_{t-1}
      if (tid == 0) {
        while (__hip_atomic_load(flag_pt, __ATOMIC_ACQUIRE,
                                 __HIP_MEMORY_SCOPE_AGENT) < t)
          __builtin_amdgcn_s_sleep(1);
      }
      __syncthreads();
      if (tid < 128)
        hbuf[(1 - half) * 128 + tid] = __hip_atomic_load(
            &hx_pt[tid], __ATOMIC_RELAXED, __HIP_MEMORY_SCOPE_AGENT);
      __syncthreads();
      float2 o = *(const float2*)&hbuf[(1 - half) * 128 + 2 * lane];
      hp_oth = pack2(o.x, o.y);
    }

#pragma unroll
    for (int kk = 0; kk < 64; ++kk)
      acc = fdot2(w1[kk], bcast_pair(hp_oth, kk), acc);

    gbuf[tid] = acc;
    __syncthreads();

    if (tid < 128) {  // LSTM cell for own 128 dims (gates order i,f,g,o)
      float iv = sigm(gbuf[tid]);
      float fv = sigm(gbuf[tid + 128]);
      float gv = tanh_(gbuf[tid + 256]);
      float ov = sigm(gbuf[tid + 384]);
      c_st = fv * c_st + iv * gv;
      float hnew = ov * tanh_(c_st);
      hbuf[half * 128 + tid] = hnew;
      __hip_atomic_store(&hx_me[tid], hnew, __ATOMIC_RELAXED,
                         __HIP_MEMORY_SCOPE_AGENT);
      if (LAYER == 0) {
        if ((t & 1) == 0)
          Hout[((size_t)b * 512 + (t >> 1)) * 256 + half * 128 + tid] = (f16)hnew;
      } else if (LAYER == 1) {
        if ((t & 1) == 0)
          Hout[((size_t)b * 256 + (t >> 1)) * 256 + half * 128 + tid] = (f16)hnew;
      } else {
        size_t base = ((size_t)b * 1024 + (size_t)t * 4) * 256 + half * 128 + tid;
        y[base] = hnew;
        y[base + 256] = hnew;
        y[base + 512] = hnew;
        y[base + 768] = hnew;
      }
    }
    __syncthreads();  // drains all waves' vmcnt -> hx stores visible at MALL
    if (tid == 0)
      __hip_atomic_store(flag_me, t + 1, __ATOMIC_RELEASE,
                         __HIP_MEMORY_SCOPE_AGENT);
    float2 a = *(const float2*)&hbuf[half * 128 + 2 * lane];
    hp_own = pack2(a.x, a.y);
  }

  // save chunk state (own half; partner WG writes its half)
  if (tid < 128) {
    hstate[b * 256 + half * 128 + tid] = hbuf[half * 128 + tid];
    cstate[b * 256 + half * 128 + tid] = c_st;
  }
}

// ---------------- orchestration ----------------

extern "C" void kernel_launch(void* const* d_in, const int* in_sizes, int n_in,
                              void* d_out, int out_size, void* d_ws, size_t ws_size,
                              hipStream_t stream) {
  const float* x = (const float*)d_in[0];
  const float* wih[3] = {(const float*)d_in[1], (const float*)d_in[5], (const float*)d_in[9]};
  const float* whh[3] = {(const float*)d_in[2], (const float*)d_in[6], (const float*)d_in[10]};
  const float* bi[3] = {(const float*)d_in[3], (const float*)d_in[7], (const float*)d_in[11]};
  const float* bh[3] = {(const float*)d_in[4], (const float*)d_in[8], (const float*)d_in[12]};
  float* y = (float*)d_out;

  // workspace layout (~155 MB total)
  char* p = (char*)d_ws;
  f16* Xf = (f16*)p;        p += (size_t)16777216 * 2;       // 33.5 MB
  f16* Wih0f = (f16*)p;     p += (size_t)131072 * 2;
  f16* Whh0f = (f16*)p;     p += (size_t)262144 * 2;
  f16* Wih1f = (f16*)p;     p += (size_t)262144 * 2;
  f16* Whh1f = (f16*)p;     p += (size_t)262144 * 2;
  f16* Wih2f = (f16*)p;     p += (size_t)262144 * 2;
  f16* Whh2f = (f16*)p;     p += (size_t)262144 * 2;
  float* bias0 = (float*)p; p += 4096;
  float* bias1 = (float*)p; p += 4096;
  float* bias2 = (float*)p; p += 4096;
  f16* Gbuf = (f16*)p;      p += (size_t)32768 * 1024 * 2;   // 67 MB chunk
  f16* H0e = (f16*)p;       p += (size_t)128 * 512 * 256 * 2; // 33.5 MB
  f16* H1q = (f16*)p;       p += (size_t)128 * 256 * 256 * 2; // 16.8 MB
  float* hstate = (float*)p; p += (size_t)128 * 256 * 4;
  float* cstate = (float*)p; p += (size_t)128 * 256 * 4;
  float* hx0 = (float*)p;   p += (size_t)128 * 256 * 4;
  float* hx1 = (float*)p;   p += (size_t)128 * 256 * 4;
  float* hx2 = (float*)p;   p += (size_t)128 * 256 * 4;
  int* flags0 = (int*)p;    p += 4096;   // poisoned 0xAA.. = negative -> safe init
  int* flags1 = (int*)p;    p += 4096;
  int* flags2 = (int*)p;    p += 4096;

  // prep
  k_cvt_x<<<4096, 256, 0, stream>>>((const float2*)x, (v2h*)Xf, 8388608);
  k_prep_w<<<1024, 256, 0, stream>>>(wih[0], whh[0], wih[1], whh[1], wih[2], whh[2],
                                     bi[0], bh[0], bi[1], bh[1], bi[2], bh[2],
                                     Wih0f, Whh0f, Wih1f, Whh1f, Wih2f, Whh2f,
                                     bias0, bias1, bias2);

  // layer 0: 4 chunks of 256 steps
  for (int c = 0; c < 4; ++c) {
    k_gemm<128><<<512, 256, 0, stream>>>(Xf, 1024, c * 256, Wih0f, bias0, Gbuf);
    k_rec<0><<<256, 512, 0, stream>>>(Gbuf, Whh0f, c * 256, 256, H0e, nullptr,
                                      hstate, cstate, hx0, flags0);
  }
  // layer 1: 2 chunks of 256 steps (inputs = h0 at even t)
  for (int c = 0; c < 2; ++c) {
    k_gemm<256><<<512, 256, 0, stream>>>(H0e, 512, c * 256, Wih1f, bias1, Gbuf);
    k_rec<1><<<256, 512, 0, stream>>>(Gbuf, Whh1f, c * 256, 256, H1q, nullptr,
                                      hstate, cstate, hx1, flags1);
  }
  // layer 2: 1 chunk of 256 steps (inputs = h1 at t%4==0); writes y with 4x broadcast
  k_gemm<256><<<512, 256, 0, stream>>>(H1q, 256, 0, Wih2f, bias2, Gbuf);
  k_rec<2><<<256, 512, 0, stream>>>(Gbuf, Whh2f, 0, 256, nullptr, y,
                                    hstate, cstate, hx2, flags2);
}

// Round 3
// 4735.252 us; speedup vs baseline: 2.7229x; 2.7229x over previous
//
#include <hip/hip_runtime.h>
#include <hip/hip_fp16.h>
#include <stdint.h>
#include <stddef.h>

// DRNN (dilated 3-layer LSTM), B=128, T=1024, F=128, H=256, dil=[1,2,4].
//  - Input GEMMs hoisted out of recurrence (f16 MFMA 16x16x32), G in 67MB chunks.
//  - Recurrence: batch element -> PAIR of WGs (512 gate cols each), W_hh in VGPRs,
//    h broadcast via v_readlane + v_dot2_f32_f16.
//  - R3 change: pair exchange via SINGLE-WORD relaxed agent atomics {tag32 | f16x2},
//    parity double-buffered. No acquire/release fences (they emit L2 wb/inv on
//    gfx950 -> measured 8us/step stall in R2). Per-lane polling, 2 barriers/step.

typedef _Float16 f16;
typedef _Float16 v2h __attribute__((ext_vector_type(2)));
typedef _Float16 v8h __attribute__((ext_vector_type(8)));
typedef __fp16 h2_raw __attribute__((ext_vector_type(2)));
typedef __fp16 h8_raw __attribute__((ext_vector_type(8)));
typedef float v4f __attribute__((ext_vector_type(4)));
typedef unsigned long long u64;

#define DEVINL static __device__ __forceinline__

DEVINL float sigm(float x) { return 1.0f / (1.0f + __expf(-x)); }
DEVINL float tanh_(float x) {
  x = fminf(fmaxf(x, -15.0f), 15.0f);
  float e = __expf(-2.0f * x);
  return (1.0f - e) / (1.0f + e);
}
DEVINL v2h pack2(float a, float b) {
  return __builtin_bit_cast(v2h, __builtin_amdgcn_cvt_pkrtz(a, b));
}
DEVINL v2h bcast_pair(v2h v, int l) {
  int i = __builtin_bit_cast(int, v);
  i = __builtin_amdgcn_readlane(i, l);
  return __builtin_bit_cast(v2h, i);
}
DEVINL float fdot2(v2h a, v2h b, float c) {
  return __builtin_amdgcn_fdot2(__builtin_bit_cast(h2_raw, a),
                                __builtin_bit_cast(h2_raw, b), c, false);
}
DEVINL v4f mfma_16x16x32(v8h a, v8h b, v4f c) {
  return __builtin_amdgcn_mfma_f32_16x16x32_f16(__builtin_bit_cast(h8_raw, a),
                                                __builtin_bit_cast(h8_raw, b), c,
                                                0, 0, 0);
}

// ---------------- prep ----------------

__global__ void k_cvt_x(const float2* __restrict__ src, v2h* __restrict__ dst, int n2) {
  int i = blockIdx.x * blockDim.x + threadIdx.x;
  int st = gridDim.x * blockDim.x;
  for (; i < n2; i += st) {
    float2 v = src[i];
    dst[i] = pack2(v.x, v.y);
  }
}

__global__ void k_prep_w(const float* __restrict__ wih0, const float* __restrict__ whh0,
                         const float* __restrict__ wih1, const float* __restrict__ whh1,
                         const float* __restrict__ wih2, const float* __restrict__ whh2,
                         const float* __restrict__ bi0, const float* __restrict__ bh0,
                         const float* __restrict__ bi1, const float* __restrict__ bh1,
                         const float* __restrict__ bi2, const float* __restrict__ bh2,
                         f16* wih0f, f16* whh0f, f16* wih1f, f16* whh1f,
                         f16* wih2f, f16* whh2f,
                         float* bias0, float* bias1, float* bias2) {
  int i = blockIdx.x * blockDim.x + threadIdx.x;  // grid covers 262144
  if (i < 131072) wih0f[i] = (f16)wih0[i];
  whh0f[i] = (f16)whh0[i];
  wih1f[i] = (f16)wih1[i];
  whh1f[i] = (f16)whh1[i];
  wih2f[i] = (f16)wih2[i];
  whh2f[i] = (f16)whh2[i];
  if (i < 1024) {
    bias0[i] = bi0[i] + bh0[i];
    bias1[i] = bi1[i] + bh1[i];
    bias2[i] = bi2[i] + bh2[i];
  }
}

// ---------------- input GEMM (unchanged from R2; not a bottleneck) ----------------

template <int K>
__launch_bounds__(256)
__global__ void k_gemm(const f16* __restrict__ A, int Tb, int t0,
                       const f16* __restrict__ W, const float* __restrict__ bias,
                       f16* __restrict__ G) {
  constexpr int LDK = K + 8;
  __shared__ f16 As[64 * LDK];
  int b = blockIdx.x >> 2, tb = blockIdx.x & 3;
  const f16* Ablk = A + ((size_t)b * Tb + t0 + tb * 64) * K;
  int tid = threadIdx.x;

  constexpr int NV = 64 * K / 8;
  const uint4* src = (const uint4*)Ablk;
  for (int i = tid; i < NV; i += 256) {
    int e = i * 8;
    int r = e / K, c0 = e % K;
    *(uint4*)&As[r * LDK + c0] = src[i];
  }
  __syncthreads();

  int wave = tid >> 6, lane = tid & 63;
  int lm = lane & 15, lk = (lane >> 4) * 8;

  v8h af[K / 32];
#pragma unroll
  for (int kc = 0; kc < K / 32; ++kc)
    af[kc] = *(const v8h*)&As[(wave * 16 + lm) * LDK + kc * 32 + lk];

  size_t grow0 = (size_t)b * 256 + tb * 64 + wave * 16;
  for (int nt = 0; nt < 64; ++nt) {
    v4f acc = {0.0f, 0.0f, 0.0f, 0.0f};
    const f16* Wrow = W + (size_t)(nt * 16 + lm) * K + lk;
#pragma unroll
    for (int kc = 0; kc < K / 32; ++kc) {
      v8h bf = *(const v8h*)(Wrow + kc * 32);
      acc = mfma_16x16x32(af[kc], bf, acc);
    }
    float bv = bias[nt * 16 + lm];
#pragma unroll
    for (int r = 0; r < 4; ++r) {
      int m = (lane >> 4) * 4 + r;
      G[(grow0 + m) * 1024 + nt * 16 + lm] = (f16)(acc[r] + bv);
    }
  }
}

// ---------------- recurrence ----------------
// grid 256 x 512 threads. b=blk>>1, half=blk&1 owns gate cols for h dims
// [half*128, half*128+128) across all 4 gates. W_hh row (256 f16) per thread in
// 128 v2h regs, split own-half k / partner-half k.
// Exchange: hxw[(b*2+half)*128 + parity*64 + w] = {tag=t+1 (int32 hi) | f16x2 h}.
// Parity = t&1 double-buffer makes overwrite-while-reading impossible (overwrite
// of buf[p] with h_{t+1} requires partner finished step t+1, which requires OUR
// h_t publish, which happens after our read of h_{t-1} from buf[p]).

template <int LAYER>
__launch_bounds__(512, 2)
__global__ void k_rec(const f16* __restrict__ G,   // chunk [128][256][1024] f16
                      const f16* __restrict__ Whh, // [1024][256] f16
                      int t0, int steps,
                      f16* __restrict__ Hout, float* __restrict__ y,
                      float* __restrict__ hstate, float* __restrict__ cstate,
                      u64* hxw) {
  int blk = blockIdx.x;
  int b = blk >> 1, half = blk & 1;
  int tid = threadIdx.x;
  int lane = tid & 63;
  int g = tid >> 7, j = tid & 127;
  int col = g * 256 + half * 128 + j;

  __shared__ float gbuf[512];
  __shared__ uint32_t hbufw[64];  // own-half h, packed f16x2 per word

  // W_hh row for this col -> registers. w0: own-half k, w1: partner-half k.
  v2h w0[64], w1[64];
  {
    const v8h* wown = (const v8h*)(Whh + (size_t)col * 256 + half * 128);
    const v8h* woth = (const v8h*)(Whh + (size_t)col * 256 + (1 - half) * 128);
#pragma unroll
    for (int i = 0; i < 16; ++i) {
      v8h qa = wown[i], qb = woth[i];
#pragma unroll
      for (int p = 0; p < 4; ++p) {
        v2h ta, tb;
        ta[0] = qa[2 * p]; ta[1] = qa[2 * p + 1];
        tb[0] = qb[2 * p]; tb[1] = qb[2 * p + 1];
        w0[i * 4 + p] = ta;
        w1[i * 4 + p] = tb;
      }
    }
  }

  u64* myw = hxw + (size_t)(b * 2 + half) * 128;
  const u64* pw = hxw + (size_t)(b * 2 + (1 - half)) * 128;

  float c_st = 0.0f, last_h = 0.0f;
  v2h hp_own = pack2(0.0f, 0.0f), hp_oth = pack2(0.0f, 0.0f);

  if (t0 > 0) {  // restore own-half state (partner half arrives via word poll)
    float2 a = *(const float2*)&hstate[b * 256 + half * 128 + 2 * lane];
    hp_own = pack2(a.x, a.y);
    if (tid < 128) {
      last_h = hstate[b * 256 + half * 128 + tid];
      c_st = cstate[b * 256 + half * 128 + tid];
    }
  }

  const f16* Gp = G + (size_t)b * 256 * 1024 + col;
  float gcur = (float)Gp[0];

  for (int s = 0; s < steps; ++s) {
    int t = t0 + s;

    // issue partner poll + next-G prefetch early; own-half dots hide the latency
    const u64* pwp = pw + (((t - 1) & 1) << 6) + lane;
    u64 wp = 0;
    if (t > 0)
      wp = __hip_atomic_load(pwp, __ATOMIC_RELAXED, __HIP_MEMORY_SCOPE_AGENT);
    float gnext = (s + 1 < steps) ? (float)Gp[(size_t)(s + 1) << 10] : 0.0f;

    float acc = gcur;
#pragma unroll
    for (int kk = 0; kk < 64; ++kk)
      acc = fdot2(w0[kk], bcast_pair(hp_own, kk), acc);

    if (t > 0) {  // tag+payload in one atomic word: no fence needed
      while ((int)(wp >> 32) < t)
        wp = __hip_atomic_load(pwp, __ATOMIC_RELAXED, __HIP_MEMORY_SCOPE_AGENT);
      hp_oth = __builtin_bit_cast(v2h, (uint32_t)wp);
    }

#pragma unroll
    for (int kk = 0; kk < 64; ++kk)
      acc = fdot2(w1[kk], bcast_pair(hp_oth, kk), acc);

    gbuf[tid] = acc;
    __syncthreads();

    if (tid < 128) {  // LSTM cell for own 128 dims (gate order i,f,g,o)
      float iv = sigm(gbuf[tid]);
      float fv = sigm(gbuf[tid + 128]);
      float gv = tanh_(gbuf[tid + 256]);
      float ov = sigm(gbuf[tid + 384]);
      c_st = fv * c_st + iv * gv;
      float hnew = ov * tanh_(c_st);
      last_h = hnew;
      float hn1 = __shfl_down(hnew, 1, 64);
      if ((tid & 1) == 0) {  // publish FIRST (shortest cross-WG path)
        uint32_t pk = __builtin_bit_cast(uint32_t, pack2(hnew, hn1));
        u64 wv = ((u64)(uint32_t)(t + 1) << 32) | (u64)pk;
        __hip_atomic_store(&myw[((t & 1) << 6) + (tid >> 1)], wv,
                           __ATOMIC_RELAXED, __HIP_MEMORY_SCOPE_AGENT);
        hbufw[tid >> 1] = pk;
      }
      if (LAYER == 0) {
        if ((t & 1) == 0)
          Hout[((size_t)b * 512 + (t >> 1)) * 256 + half * 128 + tid] = (f16)hnew;
      } else if (LAYER == 1) {
        if ((t & 1) == 0)
          Hout[((size_t)b * 256 + (t >> 1)) * 256 + half * 128 + tid] = (f16)hnew;
      } else {
        size_t base = ((size_t)b * 1024 + (size_t)t * 4) * 256 + half * 128 + tid;
        y[base] = hnew;
        y[base + 256] = hnew;
        y[base + 512] = hnew;
        y[base + 768] = hnew;
      }
    }
    __syncthreads();
    hp_own = __builtin_bit_cast(v2h, hbufw[lane]);
    gcur = gnext;
  }

  if (tid < 128) {  // chunk state (own half; partner writes its half)
    hstate[b * 256 + half * 128 + tid] = last_h;
    cstate[b * 256 + half * 128 + tid] = c_st;
  }
}

// ---------------- orchestration ----------------

extern "C" void kernel_launch(void* const* d_in, const int* in_sizes, int n_in,
                              void* d_out, int out_size, void* d_ws, size_t ws_size,
                              hipStream_t stream) {
  const float* x = (const float*)d_in[0];
  const float* wih[3] = {(const float*)d_in[1], (const float*)d_in[5], (const float*)d_in[9]};
  const float* whh[3] = {(const float*)d_in[2], (const float*)d_in[6], (const float*)d_in[10]};
  const float* bi[3] = {(const float*)d_in[3], (const float*)d_in[7], (const float*)d_in[11]};
  const float* bh[3] = {(const float*)d_in[4], (const float*)d_in[8], (const float*)d_in[12]};
  float* y = (float*)d_out;

  // workspace layout (~155 MB total)
  char* p = (char*)d_ws;
  f16* Xf = (f16*)p;        p += (size_t)16777216 * 2;        // 33.5 MB
  f16* Wih0f = (f16*)p;     p += (size_t)131072 * 2;
  f16* Whh0f = (f16*)p;     p += (size_t)262144 * 2;
  f16* Wih1f = (f16*)p;     p += (size_t)262144 * 2;
  f16* Whh1f = (f16*)p;     p += (size_t)262144 * 2;
  f16* Wih2f = (f16*)p;     p += (size_t)262144 * 2;
  f16* Whh2f = (f16*)p;     p += (size_t)262144 * 2;
  float* bias0 = (float*)p; p += 4096;
  float* bias1 = (float*)p; p += 4096;
  float* bias2 = (float*)p; p += 4096;
  f16* Gbuf = (f16*)p;      p += (size_t)32768 * 1024 * 2;    // 67 MB chunk
  f16* H0e = (f16*)p;       p += (size_t)128 * 512 * 256 * 2; // 33.5 MB
  f16* H1q = (f16*)p;       p += (size_t)128 * 256 * 256 * 2; // 16.8 MB
  float* hstate = (float*)p; p += (size_t)128 * 256 * 4;
  float* cstate = (float*)p; p += (size_t)128 * 256 * 4;
  u64* hxw0 = (u64*)p;      p += (size_t)128 * 2 * 128 * 8;   // 256 KB, tagged words
  u64* hxw1 = (u64*)p;      p += (size_t)128 * 2 * 128 * 8;   // (poison 0xAA.. -> tag<0)
  u64* hxw2 = (u64*)p;      p += (size_t)128 * 2 * 128 * 8;

  // prep
  k_cvt_x<<<4096, 256, 0, stream>>>((const float2*)x, (v2h*)Xf, 8388608);
  k_prep_w<<<1024, 256, 0, stream>>>(wih[0], whh[0], wih[1], whh[1], wih[2], whh[2],
                                     bi[0], bh[0], bi[1], bh[1], bi[2], bh[2],
                                     Wih0f, Whh0f, Wih1f, Whh1f, Wih2f, Whh2f,
                                     bias0, bias1, bias2);

  // layer 0: 4 chunks of 256 steps
  for (int c = 0; c < 4; ++c) {
    k_gemm<128><<<512, 256, 0, stream>>>(Xf, 1024, c * 256, Wih0f, bias0, Gbuf);
    k_rec<0><<<256, 512, 0, stream>>>(Gbuf, Whh0f, c * 256, 256, H0e, nullptr,
                                      hstate, cstate, hxw0);
  }
  // layer 1: 2 chunks of 256 steps (inputs = h0 at even t)
  for (int c = 0; c < 2; ++c) {
    k_gemm<256><<<512, 256, 0, stream>>>(H0e, 512, c * 256, Wih1f, bias1, Gbuf);
    k_rec<1><<<256, 512, 0, stream>>>(Gbuf, Whh1f, c * 256, 256, H1q, nullptr,
                                      hstate, cstate, hxw1);
  }
  // layer 2: 1 chunk of 256 steps (inputs = h1 at t%4==0); writes y with 4x broadcast
  k_gemm<256><<<512, 256, 0, stream>>>(H1q, 256, 0, Wih2f, bias2, Gbuf);
  k_rec<2><<<256, 512, 0, stream>>>(Gbuf, Whh2f, 0, 256, nullptr, y,
                                    hstate, cstate, hxw2);
}